// Round 1
// 472.108 us; speedup vs baseline: 1.1619x; 1.1619x over previous
//
#include <hip/hip_runtime.h>
#include <hip/hip_bf16.h>
#include <math.h>

typedef __bf16 bf16_t;
typedef __bf16 bf16x8 __attribute__((ext_vector_type(8)));
typedef float f32x4 __attribute__((ext_vector_type(4)));

// ---------------------------------------------------------------------------
// Problem constants: B=4, H=64, W=128, C=512, F=1024, WS=4, SS=2, NH=8, hd=64.
// M = 32768 token rows. 2048 windows total.
// ---------------------------------------------------------------------------

#define X1_OFF   0u            // x1 fp32 residual [32768,512] = 64 MB
#define XW_OFF   67108864u     // xw -> O -> h2 (bf16, 32 MB)
#define QKV_OFF  100663296u    // qkv -> gelu-out a (bf16, 96 MB)
#define WQ_OFF   201326592u
#define WP_OFF   202899456u
#define W1_OFF   203423744u
#define W2_OFF   204472320u
#define SV_OFF   205520896u
#define FLAG_OFF 205545472u
// SV float offsets: g1=0 be1=512 bq=1024 bp=2560 g2=3072 be2=3584 b1=4096
//                   b2=5120 rpb=5632 (end 6024)

__device__ __forceinline__ int perm_row(int r) {
    int b   = r >> 13;
    int rem = r & 8191;
    int w   = rem >> 4;
    int n   = rem & 15;
    int wy  = w >> 5, wx = w & 31;
    int y   = wy * 4 + (n >> 2);
    int x   = wx * 4 + (n & 3);
    int ys  = (y + 2) & 63;
    int xs  = (x + 2) & 127;
    return (b << 13) + (ys << 7) + xs;
}

// global->LDS direct load, 16 B per lane: pass per-lane global addr + wave-uniform
// LDS base; HW scatters lane i -> base + i*16.
__device__ __forceinline__ void gld16(const void* g, void* l) {
    __builtin_amdgcn_global_load_lds(
        (const __attribute__((address_space(1))) unsigned int*)(unsigned long long)(uintptr_t)g,
        (__attribute__((address_space(3))) unsigned int*)(unsigned int)(uintptr_t)l,
        16, 0, 0);
}

// ---------------- dtype probe: 1 = fp32 source, 0 = bf16 source ----------------
__global__ __launch_bounds__(256) void k_probe(const unsigned short* __restrict__ x,
                                               int n, int* __restrict__ flag) {
    __shared__ int cnt;
    if (threadIdx.x == 0) cnt = 0;
    __syncthreads();
    int c = 0;
    for (int i = threadIdx.x; i < n; i += 256) {
        int e = (x[i] >> 7) & 0xFF;
        if (e >= 0xC0) c++;
    }
    atomicAdd(&cnt, c);
    __syncthreads();
    if (threadIdx.x == 0) *flag = (cnt > 8) ? 1 : 0;
}

// ---------------- weight / small-vector normalization ----------------
__global__ __launch_bounds__(256) void k_cvt_bf16(const void* __restrict__ src,
                                                  bf16_t* __restrict__ dst, int n,
                                                  const int* __restrict__ flag) {
    int i = blockIdx.x * 256 + threadIdx.x;
    if (i >= n) return;
    dst[i] = (*flag) ? (bf16_t)((const float*)src)[i] : ((const bf16_t*)src)[i];
}

__global__ __launch_bounds__(256) void k_cvt_small(
        const void* g1, const void* be1, const void* bq, const void* bp,
        const void* g2, const void* be2, const void* b1, const void* b2,
        const void* rpb, float* __restrict__ dst, const int* __restrict__ flag) {
    int i = blockIdx.x * 256 + threadIdx.x;
    const void* src; int off;
    if      (i < 512)  { src = g1;  off = i; }
    else if (i < 1024) { src = be1; off = i - 512; }
    else if (i < 2560) { src = bq;  off = i - 1024; }
    else if (i < 3072) { src = bp;  off = i - 2560; }
    else if (i < 3584) { src = g2;  off = i - 3072; }
    else if (i < 4096) { src = be2; off = i - 3584; }
    else if (i < 5120) { src = b1;  off = i - 4096; }
    else if (i < 5632) { src = b2;  off = i - 5120; }
    else if (i < 6024) { src = rpb; off = i - 5632; }
    else return;
    dst[i] = (*flag) ? ((const float*)src)[off] : (float)((const bf16_t*)src)[off];
}

// ---------------- Kernel 1: LN1 + shift + window partition ----------------
__global__ __launch_bounds__(256) void k_ln1(const void* __restrict__ x,
                                             const float* __restrict__ g,
                                             const float* __restrict__ be,
                                             bf16_t* __restrict__ xw,
                                             const int* __restrict__ flag) {
    int r    = blockIdx.x * 4 + (threadIdx.x >> 6);
    int lane = threadIdx.x & 63;
    int f    = *flag;
    long ro  = (long)perm_row(r) * 512;
    const float*  x32 = (const float*)x + ro;
    const bf16_t* x16 = (const bf16_t*)x + ro;
    int base = lane * 8;
    float v[8];
    float s = 0.f, ss = 0.f;
#pragma unroll
    for (int j = 0; j < 8; j++) {
        float t = f ? x32[base + j] : (float)x16[base + j];
        v[j] = t; s += t; ss += t * t;
    }
#pragma unroll
    for (int off = 32; off; off >>= 1) {
        s  += __shfl_down(s,  off, 64);
        ss += __shfl_down(ss, off, 64);
    }
    s  = __shfl(s, 0, 64);
    ss = __shfl(ss, 0, 64);
    float m   = s * (1.f / 512.f);
    float var = ss * (1.f / 512.f) - m * m;
    float inv = rsqrtf(var + 1e-5f);
    bf16_t* orow = xw + (long)r * 512;
#pragma unroll
    for (int j = 0; j < 8; j++)
        orow[base + j] = (bf16_t)((v[j] - m) * inv * g[base + j] + be[base + j]);
}

// ---------------- Kernel 5: LN2 ----------------
__global__ __launch_bounds__(256) void k_ln2(const float* __restrict__ x1,
                                             const float* __restrict__ g,
                                             const float* __restrict__ be,
                                             bf16_t* __restrict__ h2) {
    int r    = blockIdx.x * 4 + (threadIdx.x >> 6);
    int lane = threadIdx.x & 63;
    const float* xr = x1 + (long)r * 512;
    int base = lane * 8;
    float v[8];
    float s = 0.f, ss = 0.f;
#pragma unroll
    for (int j = 0; j < 8; j++) {
        float t = xr[base + j];
        v[j] = t; s += t; ss += t * t;
    }
#pragma unroll
    for (int off = 32; off; off >>= 1) {
        s  += __shfl_down(s,  off, 64);
        ss += __shfl_down(ss, off, 64);
    }
    s  = __shfl(s, 0, 64);
    ss = __shfl(ss, 0, 64);
    float m   = s * (1.f / 512.f);
    float var = ss * (1.f / 512.f) - m * m;
    float inv = rsqrtf(var + 1e-5f);
    bf16_t* orow = h2 + (long)r * 512;
#pragma unroll
    for (int j = 0; j < 8; j++)
        orow[base + j] = (bf16_t)((v[j] - m) * inv * g[base + j] + be[base + j]);
}

// ---------------- 128x128-tile GEMM, BK=64, XOR-swizzled LDS, XCD swizzle --
// C = A @ W^T.  A:[M,K] bf16 rm, W:[N,K] bf16 rm. 4 waves in 2x2, each a
// 64x64 quadrant of 16x16x32 MFMAs.
//
// v2 (this round): double-buffered K-pipeline (prefetch-ahead-1). Per K-step:
//   issue 8 global_load_lds for tile t+1 into buf^1, ds_read+MFMA tile t from
//   buf, ONE __syncthreads() (its implicit vmcnt/lgkm drain is the counted
//   wait) -> prefetch latency hides under the 32 MFMAs instead of being
//   serially exposed (old structure: stage -> drain -> compute = stall-bound,
//   all pipes <26%).  LDS 68 KB -> 2 blocks/CU, same as the VGPR+AGPR cap
//   (acc[4][4]=64 AGPR + ~116 VGPR ~ 2 waves/SIMD), so dbuf is occupancy-free.
//
// v2 epilogue: each wave dumps its 64x64 f32 quadrant into a padded [64][68]
// LDS scratch (per-wave private region, reused staging memory), then reads it
// back transposed so each lane owns 8 CONSECUTIVE columns of one row ->
// 16 B vector loads/stores, full 128 B lines per instruction (old: 2-4 B
// element stores, partial-line write-allocate suspected in FETCH_SIZE).
//
// EPI: 0=bias->bf16  1=proj: x1[perm]=x+acc+bias (fp32)  2=bias+GELU->bf16
//      3=fc2: out=x1+acc+bias (flag dtype)
template<int EPI>
__global__ __launch_bounds__(256) void k_gemm128(const bf16_t* __restrict__ A,
                                                 const bf16_t* __restrict__ Wt,
                                                 const float* __restrict__ bias,
                                                 void* __restrict__ out,
                                                 const void* __restrict__ res,
                                                 const int* __restrict__ flag,
                                                 int N, int K) {
    // layout: buf b (b=0,1) at b*32768: A-tile 16 KB then B-tile 16 KB.
    // epilogue scratch: wave wv at wv*17408 bytes ([64][68] f32).
    __shared__ char smem[69632];
    int tid  = threadIdx.x;
    int lane = tid & 63, wv = tid >> 6;

    int nbx = N >> 7;
    int id  = blockIdx.x;
    int xb  = (id >> 3) % nbx;
    int yb  = ((id >> 3) / nbx) * 8 + (id & 7);
    int m0  = yb << 7, n0 = xb << 7;

    // staging addressing (XOR-swizzled chunk layout, unchanged per-buffer)
    int srow = tid >> 3;                 // 0..31
    int kc   = (tid & 7) ^ (srow & 7);   // XOR-swizzled chunk
    const bf16_t* gA = A  + (long)(m0 + srow) * K + kc * 8;
    const bf16_t* gB = Wt + (long)(n0 + srow) * K + kc * 8;

    // fragment reads
    int rr = lane & 15, quad = lane >> 4;
    int wm = (wv >> 1) * 64, wn = (wv & 1) * 64;
    int p0 = ((quad ^ (rr & 7)) * 8);    // element offset of k-chunk, ks=0

    f32x4 acc[4][4];
#pragma unroll
    for (int mi = 0; mi < 4; mi++)
#pragma unroll
        for (int ni = 0; ni < 4; ni++) { f32x4 z = {0.f,0.f,0.f,0.f}; acc[mi][ni] = z; }

    int KT = K >> 6;

    // prologue: stage tile 0 into buf 0
#pragma unroll
    for (int j = 0; j < 4; j++) {
        gld16(gA + (long)j * 32 * K, smem + j * 4096 + wv * 1024);
        gld16(gB + (long)j * 32 * K, smem + 16384 + j * 4096 + wv * 1024);
    }
    __syncthreads();

    int cur = 0;
    for (int t = 0; t < KT; t++) {
        // issue prefetch of tile t+1 FIRST (latency hides under MFMA below)
        if (t + 1 < KT) {
            const bf16_t* nA = gA + (long)(t + 1) * 64;
            const bf16_t* nB = gB + (long)(t + 1) * 64;
            char* db = smem + (cur ^ 1) * 32768;
#pragma unroll
            for (int j = 0; j < 4; j++) {
                gld16(nA + (long)j * 32 * K, db + j * 4096 + wv * 1024);
                gld16(nB + (long)j * 32 * K, db + 16384 + j * 4096 + wv * 1024);
            }
        }
        const bf16_t* rA = (const bf16_t*)(smem + cur * 32768) + (wm + rr) * 64;
        const bf16_t* rB = (const bf16_t*)(smem + cur * 32768 + 16384) + (wn + rr) * 64;
#pragma unroll
        for (int ks = 0; ks < 2; ks++) {
            int pp = ks ? (p0 ^ 32) : p0;   // chunk XOR 4 == element offset XOR 32
            bf16x8 af[4], bg[4];
#pragma unroll
            for (int i = 0; i < 4; i++) af[i] = *(const bf16x8*)(rA + i * 1024 + pp);
#pragma unroll
            for (int i = 0; i < 4; i++) bg[i] = *(const bf16x8*)(rB + i * 1024 + pp);
#pragma unroll
            for (int mi = 0; mi < 4; mi++)
#pragma unroll
                for (int ni = 0; ni < 4; ni++)
                    acc[mi][ni] = __builtin_amdgcn_mfma_f32_16x16x32_bf16(af[mi], bg[ni], acc[mi][ni], 0, 0, 0);
        }
        // one barrier per K-step: implicit vmcnt(0)+lgkmcnt(0) drain here is the
        // counted wait for the prefetched tile (issued before compute above);
        // also guarantees all waves finished reading buf[cur] before iteration
        // t+1 overwrites it.
        __syncthreads();
        cur ^= 1;
    }

    // ---------------- vectorized epilogue via per-wave LDS transpose -------
    // after the final in-loop barrier every wave is done with staging buffers;
    // each wave writes only its private 17408 B region -> no extra barrier.
    float* sc = (float*)smem + wv * 4352;   // [64][68] f32, 16 B-aligned rows
#pragma unroll
    for (int mi = 0; mi < 4; mi++)
#pragma unroll
        for (int ni = 0; ni < 4; ni++)
#pragma unroll
            for (int i = 0; i < 4; i++)
                sc[(mi * 16 + quad * 4 + i) * 68 + ni * 16 + rr] = acc[mi][ni][i];

    int f = (EPI == 1 || EPI == 3) ? *flag : 0;
    int rl = lane >> 3;          // row within 8-row group
    int cl = (lane & 7) * 8;     // 8 consecutive cols per lane
#pragma unroll
    for (int p = 0; p < 8; p++) {
        int row_l = p * 8 + rl;
        f32x4 v0 = *(const f32x4*)(sc + row_l * 68 + cl);
        f32x4 v1 = *(const f32x4*)(sc + row_l * 68 + cl + 4);
        int row = m0 + wm + row_l;
        int col = n0 + wn + cl;
        f32x4 b0 = *(const f32x4*)(bias + col);
        f32x4 b1 = *(const f32x4*)(bias + col + 4);
        v0 += b0; v1 += b1;

        if (EPI == 0) {
            bf16x8 ob;
#pragma unroll
            for (int c = 0; c < 4; c++) { ob[c] = (bf16_t)v0[c]; ob[c + 4] = (bf16_t)v1[c]; }
            *(bf16x8*)((bf16_t*)out + (long)row * N + col) = ob;
        } else if (EPI == 1) {
            long o = (long)perm_row(row) * 512 + col;
            if (f) {
                f32x4 r0 = *(const f32x4*)((const float*)res + o);
                f32x4 r1 = *(const f32x4*)((const float*)res + o + 4);
                v0 += r0; v1 += r1;
            } else {
                bf16x8 rb = *(const bf16x8*)((const bf16_t*)res + o);
#pragma unroll
                for (int c = 0; c < 4; c++) { v0[c] += (float)rb[c]; v1[c] += (float)rb[c + 4]; }
            }
            *(f32x4*)((float*)out + o)     = v0;
            *(f32x4*)((float*)out + o + 4) = v1;
        } else if (EPI == 2) {
            bf16x8 ob;
#pragma unroll
            for (int c = 0; c < 4; c++) {
                float a0 = v0[c], a1 = v1[c];
                ob[c]     = (bf16_t)(0.5f * a0 * (1.f + erff(a0 * 0.70710678118654752f)));
                ob[c + 4] = (bf16_t)(0.5f * a1 * (1.f + erff(a1 * 0.70710678118654752f)));
            }
            *(bf16x8*)((bf16_t*)out + (long)row * N + col) = ob;
        } else {
            long o = (long)row * 512 + col;
            f32x4 r0 = *(const f32x4*)((const float*)res + o);
            f32x4 r1 = *(const f32x4*)((const float*)res + o + 4);
            v0 += r0; v1 += r1;
            if (f) {
                *(f32x4*)((float*)out + o)     = v0;
                *(f32x4*)((float*)out + o + 4) = v1;
            } else {
                bf16x8 ob;
#pragma unroll
                for (int c = 0; c < 4; c++) { ob[c] = (bf16_t)v0[c]; ob[c + 4] = (bf16_t)v1[c]; }
                *(bf16x8*)((bf16_t*)out + o) = ob;
            }
        }
    }
}

// ---------------- Kernel 3: windowed attention ----------------
__global__ __launch_bounds__(256) void k_attn(const bf16_t* __restrict__ qkv,
                                              const float* __restrict__ rpb,
                                              bf16_t* __restrict__ O) {
    __shared__ float q[16][68], k[16][68], v[16][68];
    __shared__ float S[16][17];

    int blk = blockIdx.x;
    int h   = blk & 7;
    int w   = blk >> 3;
    int tid = threadIdx.x;

    int n0 = tid >> 4;
    int d0 = (tid & 15) * 4;
    const bf16_t* base = qkv + (long)(w * 16 + n0) * 1536 + h * 64 + d0;
#pragma unroll
    for (int j = 0; j < 4; j++) {
        q[n0][d0 + j] = (float)base[j] * 0.125f;
        k[n0][d0 + j] = (float)base[512 + j];
        v[n0][d0 + j] = (float)base[1024 + j];
    }
    __syncthreads();

    int i = tid >> 4, j = tid & 15;
    float s = 0.f;
#pragma unroll
    for (int d = 0; d < 64; d++) s += q[i][d] * k[j][d];

    int iy = i >> 2, ix = i & 3, jy = j >> 2, jx = j & 3;
    s += rpb[((iy - jy + 3) * 7 + (ix - jx + 3)) * 8 + h];

    int wl = w & 511;
    int wy = wl >> 5, wx = wl & 31;
    int yi = wy * 4 + iy, xi = wx * 4 + ix;
    int yj = wy * 4 + jy, xj = wx * 4 + jx;
    int ri = (yi < 60 ? 0 : (yi < 62 ? 1 : 2)) * 3 + (xi < 124 ? 0 : (xi < 126 ? 1 : 2));
    int rj = (yj < 60 ? 0 : (yj < 62 ? 1 : 2)) * 3 + (xj < 124 ? 0 : (xj < 126 ? 1 : 2));
    if (ri != rj) s -= 100.f;
    S[i][j] = s;
    __syncthreads();

    if (tid < 16) {
        float mx = -1e30f;
#pragma unroll
        for (int c = 0; c < 16; c++) mx = fmaxf(mx, S[tid][c]);
        float sum = 0.f;
#pragma unroll
        for (int c = 0; c < 16; c++) { float e = expf(S[tid][c] - mx); S[tid][c] = e; sum += e; }
        float invs = 1.f / sum;
#pragma unroll
        for (int c = 0; c < 16; c++) S[tid][c] *= invs;
    }
    __syncthreads();

#pragma unroll
    for (int t = 0; t < 4; t++) {
        int e  = tid + t * 256;
        int oi = e >> 6, od = e & 63;
        float acc = 0.f;
#pragma unroll
        for (int c = 0; c < 16; c++) acc += S[oi][c] * v[c][od];
        O[(long)(w * 16 + oi) * 512 + h * 64 + od] = (bf16_t)acc;
    }
}

// ---------------------------------------------------------------------------
extern "C" void kernel_launch(void* const* d_in, const int* in_sizes, int n_in,
                              void* d_out, int out_size, void* d_ws, size_t ws_size,
                              hipStream_t stream) {
    char* ws = (char*)d_ws;
    float*  x1   = (float*)(ws + X1_OFF);
    bf16_t* xw   = (bf16_t*)(ws + XW_OFF);    // xw -> O -> h2
    bf16_t* qkv  = (bf16_t*)(ws + QKV_OFF);   // qkv -> gelu-out a
    bf16_t* wq_b = (bf16_t*)(ws + WQ_OFF);
    bf16_t* wp_b = (bf16_t*)(ws + WP_OFF);
    bf16_t* w1_b = (bf16_t*)(ws + W1_OFF);
    bf16_t* w2_b = (bf16_t*)(ws + W2_OFF);
    float*  sv   = (float*)(ws + SV_OFF);
    int*    flag = (int*)(ws + FLAG_OFF);

    k_probe<<<1, 256, 0, stream>>>((const unsigned short*)d_in[0], 4096, flag);
    k_cvt_bf16<<<3072, 256, 0, stream>>>(d_in[3],  wq_b, 786432, flag);
    k_cvt_bf16<<<1024, 256, 0, stream>>>(d_in[6],  wp_b, 262144, flag);
    k_cvt_bf16<<<2048, 256, 0, stream>>>(d_in[10], w1_b, 524288, flag);
    k_cvt_bf16<<<2048, 256, 0, stream>>>(d_in[12], w2_b, 524288, flag);
    k_cvt_small<<<24,  256, 0, stream>>>(d_in[1], d_in[2], d_in[4], d_in[7],
                                         d_in[8], d_in[9], d_in[11], d_in[13],
                                         d_in[5], sv, flag);

    k_ln1<<<dim3(8192), dim3(256), 0, stream>>>(d_in[0], sv, sv + 512, xw, flag);
    k_gemm128<0><<<dim3(3072), dim3(256), 0, stream>>>(xw, wq_b, sv + 1024, qkv, nullptr, flag, 1536, 512);
    k_attn<<<dim3(16384), dim3(256), 0, stream>>>(qkv, sv + 5632, xw /*O*/);
    k_gemm128<1><<<dim3(1024), dim3(256), 0, stream>>>(xw, wp_b, sv + 2560, x1, d_in[0], flag, 512, 512);
    k_ln2<<<dim3(8192), dim3(256), 0, stream>>>(x1, sv + 3072, sv + 3584, xw /*h2*/);
    k_gemm128<2><<<dim3(2048), dim3(256), 0, stream>>>(xw, w1_b, sv + 4096, qkv /*a*/, nullptr, flag, 1024, 512);
    k_gemm128<3><<<dim3(1024), dim3(256), 0, stream>>>(qkv, w2_b, sv + 5120, d_out, x1, flag, 512, 1024);
}